// Round 1
// baseline (126.607 us; speedup 1.0000x reference)
//
#include <hip/hip_runtime.h>

// YOLOv1 loss: N=8192, S=7, C=30. One thread per grid cell.
// Per cell: read p[30], t[30], compute loss contribution, reduce to scalar.

#define CELLS_PER_SAMPLE 49
#define NCH 30

__device__ __forceinline__ float iou_f(float a0, float a1, float a2, float a3,
                                       float b0, float b1, float b2, float b3) {
    float xl = fmaxf(a0, b0);
    float yt = fmaxf(a1, b1);
    float xr = fminf(a2, b2);
    float yb = fminf(a3, b3);
    float ix = fmaxf(xr - xl, 0.0f);
    float iy = fmaxf(yb - yt, 0.0f);
    float inter = ix * iy;
    float aa = fabsf((a2 - a0) * (a3 - a1));
    float ba = fabsf((b2 - b0) * (b3 - b1));
    return inter / (aa + ba - inter + 1e-7f);
}

__global__ __launch_bounds__(256) void yolo_loss_kernel(
    const float* __restrict__ p_all, const float* __restrict__ t_all,
    float* __restrict__ out, int ncells, float inv_n)
{
    int idx = blockIdx.x * blockDim.x + threadIdx.x;
    float cell_loss = 0.0f;

    if (idx < ncells) {
        int rem = idx % CELLS_PER_SAMPLE;
        int ci = rem / 7;   // row
        int cj = rem % 7;   // col

        const float2* p2 = reinterpret_cast<const float2*>(p_all + (size_t)idx * NCH);
        const float2* t2 = reinterpret_cast<const float2*>(t_all + (size_t)idx * NCH);

        float pv[NCH], tv[NCH];
        #pragma unroll
        for (int k = 0; k < NCH / 2; ++k) {
            float2 v = p2[k]; pv[2 * k] = v.x; pv[2 * k + 1] = v.y;
            float2 w = t2[k]; tv[2 * k] = w.x; tv[2 * k + 1] = w.y;
        }

        float ltx = (float)cj / 7.0f;
        float lty = (float)ci / 7.0f;

        float coord = (tv[4] > 0.0f) ? 1.0f : 0.0f;
        float noobj = (tv[4] == 0.0f) ? 1.0f : 0.0f;

        // predicted box 1 (center-offset/size parametrization)
        float b1x1 = ltx + pv[0] / 7.0f - pv[2] * 0.5f;
        float b1y1 = lty + pv[1] / 7.0f - pv[3] * 0.5f;
        float b1x2 = pv[2] + b1x1;
        float b1y2 = pv[3] + b1y1;

        // predicted box 2 (faithful to reference: p[5:7]*(1/S - 0.5))
        const float C2 = (float)(1.0 / 7.0 - 0.5);
        float b2x1 = ltx + pv[5] * C2;
        float b2y1 = lty + pv[6] * C2;
        float b2x2 = pv[7] + b2x1;
        float b2y2 = pv[8] + b2y1;

        // target box
        float tbx1 = ltx + tv[0] / 7.0f - tv[2] * 0.5f;
        float tby1 = lty + tv[1] / 7.0f - tv[3] * 0.5f;
        float tbx2 = tv[2] + tbx1;
        float tby2 = tv[3] + tby1;

        float iou1 = iou_f(b1x1, b1y1, b1x2, b1y2, tbx1, tby1, tbx2, tby2);
        float iou2 = iou_f(b2x1, b2y1, b2x2, b2y2, tbx1, tby1, tbx2, tby2);

        bool sel = (iou1 >= iou2);
        float bx = sel ? pv[0] : pv[5];
        float by = sel ? pv[1] : pv[6];
        float bw = sel ? pv[2] : pv[7];
        float bh = sel ? pv[3] : pv[8];
        float bc = sel ? pv[4] : pv[9];

        // xy
        float dx = bx - tv[0];
        float dy = by - tv[1];
        float xy_se = dx * dx + dy * dy;

        // wh: sign(x)*sqrt(|x|), sign(0)=0
        float sw = (bw > 0.0f) ? 1.0f : ((bw < 0.0f) ? -1.0f : 0.0f);
        float sh = (bh > 0.0f) ? 1.0f : ((bh < 0.0f) ? -1.0f : 0.0f);
        float dw = sw * sqrtf(fabsf(bw)) - sqrtf(tv[2]);
        float dh = sh * sqrtf(fabsf(bh)) - sqrtf(tv[3]);
        float wh_se = dw * dw + dh * dh;

        // obj
        float mio = fmaxf(iou1, iou2);
        float dob = mio - bc;
        float obj_se = dob * dob;

        // noobj
        float d4 = pv[4] - tv[4];
        float d9 = pv[9] - tv[9];
        float noobj_se = d4 * d4 + d9 * d9;

        // labels
        float lab = 0.0f;
        #pragma unroll
        for (int k = 10; k < NCH; ++k) {
            float d = pv[k] - tv[k];
            lab += d * d;
        }

        cell_loss = coord * (5.0f * (xy_se + wh_se) + obj_se + lab)
                  + 0.5f * noobj * noobj_se;
        cell_loss *= inv_n;
    }

    // wave-64 shuffle reduction
    #pragma unroll
    for (int off = 32; off > 0; off >>= 1)
        cell_loss += __shfl_down(cell_loss, off, 64);

    __shared__ float wave_sums[4];
    int lane = threadIdx.x & 63;
    int wid  = threadIdx.x >> 6;
    if (lane == 0) wave_sums[wid] = cell_loss;
    __syncthreads();

    if (threadIdx.x == 0) {
        float s = wave_sums[0] + wave_sums[1] + wave_sums[2] + wave_sums[3];
        atomicAdd(out, s);
    }
}

extern "C" void kernel_launch(void* const* d_in, const int* in_sizes, int n_in,
                              void* d_out, int out_size, void* d_ws, size_t ws_size,
                              hipStream_t stream) {
    const float* p = (const float*)d_in[0];   // modely [N,7,7,30] f32
    const float* t = (const float*)d_in[1];   // targety [N,7,7,30] f32
    float* out = (float*)d_out;

    int ncells = in_sizes[0] / NCH;           // N*49 = 401408
    int nsamples = ncells / CELLS_PER_SAMPLE; // N = 8192

    // d_out is poisoned before every timed launch — zero it first.
    hipMemsetAsync(out, 0, sizeof(float) * (size_t)out_size, stream);

    const int threads = 256;
    int blocks = (ncells + threads - 1) / threads;
    yolo_loss_kernel<<<blocks, threads, 0, stream>>>(
        p, t, out, ncells, 1.0f / (float)nsamples);
}

// Round 2
// 121.663 us; speedup vs baseline: 1.0406x; 1.0406x over previous
//
#include <hip/hip_runtime.h>

// YOLOv1 loss: N=8192, S=7, C=30. Block = 256 threads = 256 cells.
// Stage 256 cells x 30 floats of p and t into LDS with coalesced float4
// loads, then one thread per cell computes its loss contribution from LDS.

#define CELLS_PER_SAMPLE 49
#define NCH 30
#define CPB 256                    // cells per block
#define F_PER_BLK (CPB * NCH)      // 7680 floats per array
#define V4_PER_BLK (F_PER_BLK / 4) // 1920 float4 per array

__device__ __forceinline__ float iou_f(float a0, float a1, float a2, float a3,
                                       float b0, float b1, float b2, float b3) {
    float xl = fmaxf(a0, b0);
    float yt = fmaxf(a1, b1);
    float xr = fminf(a2, b2);
    float yb = fminf(a3, b3);
    float ix = fmaxf(xr - xl, 0.0f);
    float iy = fmaxf(yb - yt, 0.0f);
    float inter = ix * iy;
    float aa = fabsf((a2 - a0) * (a3 - a1));
    float ba = fabsf((b2 - b0) * (b3 - b1));
    return inter / (aa + ba - inter + 1e-7f);
}

__global__ __launch_bounds__(256) void yolo_loss_kernel(
    const float4* __restrict__ p4, const float4* __restrict__ t4,
    float* __restrict__ out, int ncells, int nvec4, float inv_n)
{
    __shared__ float lds_p[F_PER_BLK];
    __shared__ float lds_t[F_PER_BLK];

    const int tid = threadIdx.x;
    const size_t base4 = (size_t)blockIdx.x * V4_PER_BLK;

    float4* lp4 = reinterpret_cast<float4*>(lds_p);
    float4* lt4 = reinterpret_cast<float4*>(lds_t);

    // Coalesced staging: 1920 float4 per array, 256 threads -> 7.5 iters.
    #pragma unroll
    for (int i = 0; i < 8; ++i) {
        int li = tid + i * 256;
        if (li < V4_PER_BLK) {
            size_t gi = base4 + (size_t)li;
            if (gi < (size_t)nvec4) {
                lp4[li] = p4[gi];
                lt4[li] = t4[gi];
            }
        }
    }
    __syncthreads();

    float cell_loss = 0.0f;
    const int idx = blockIdx.x * CPB + tid;

    if (idx < ncells) {
        int rem = idx % CELLS_PER_SAMPLE;
        int ci = rem / 7;   // row
        int cj = rem % 7;   // col

        const float* __restrict__ pvp = lds_p + tid * NCH;
        const float* __restrict__ tvp = lds_t + tid * NCH;

        float pv[NCH], tv[NCH];
        #pragma unroll
        for (int k = 0; k < NCH; ++k) { pv[k] = pvp[k]; tv[k] = tvp[k]; }

        float ltx = (float)cj / 7.0f;
        float lty = (float)ci / 7.0f;

        float coord = (tv[4] > 0.0f) ? 1.0f : 0.0f;
        float noobj = (tv[4] == 0.0f) ? 1.0f : 0.0f;

        // predicted box 1 (center-offset/size parametrization)
        float b1x1 = ltx + pv[0] / 7.0f - pv[2] * 0.5f;
        float b1y1 = lty + pv[1] / 7.0f - pv[3] * 0.5f;
        float b1x2 = pv[2] + b1x1;
        float b1y2 = pv[3] + b1y1;

        // predicted box 2 (faithful to reference: p[5:7]*(1/S - 0.5))
        const float C2 = (float)(1.0 / 7.0 - 0.5);
        float b2x1 = ltx + pv[5] * C2;
        float b2y1 = lty + pv[6] * C2;
        float b2x2 = pv[7] + b2x1;
        float b2y2 = pv[8] + b2y1;

        // target box
        float tbx1 = ltx + tv[0] / 7.0f - tv[2] * 0.5f;
        float tby1 = lty + tv[1] / 7.0f - tv[3] * 0.5f;
        float tbx2 = tv[2] + tbx1;
        float tby2 = tv[3] + tby1;

        float iou1 = iou_f(b1x1, b1y1, b1x2, b1y2, tbx1, tby1, tbx2, tby2);
        float iou2 = iou_f(b2x1, b2y1, b2x2, b2y2, tbx1, tby1, tbx2, tby2);

        bool sel = (iou1 >= iou2);
        float bx = sel ? pv[0] : pv[5];
        float by = sel ? pv[1] : pv[6];
        float bw = sel ? pv[2] : pv[7];
        float bh = sel ? pv[3] : pv[8];
        float bc = sel ? pv[4] : pv[9];

        // xy
        float dx = bx - tv[0];
        float dy = by - tv[1];
        float xy_se = dx * dx + dy * dy;

        // wh: sign(x)*sqrt(|x|), sign(0)=0
        float sw = (bw > 0.0f) ? 1.0f : ((bw < 0.0f) ? -1.0f : 0.0f);
        float sh = (bh > 0.0f) ? 1.0f : ((bh < 0.0f) ? -1.0f : 0.0f);
        float dw = sw * sqrtf(fabsf(bw)) - sqrtf(tv[2]);
        float dh = sh * sqrtf(fabsf(bh)) - sqrtf(tv[3]);
        float wh_se = dw * dw + dh * dh;

        // obj
        float mio = fmaxf(iou1, iou2);
        float dob = mio - bc;
        float obj_se = dob * dob;

        // noobj
        float d4 = pv[4] - tv[4];
        float d9 = pv[9] - tv[9];
        float noobj_se = d4 * d4 + d9 * d9;

        // labels
        float lab = 0.0f;
        #pragma unroll
        for (int k = 10; k < NCH; ++k) {
            float d = pv[k] - tv[k];
            lab += d * d;
        }

        cell_loss = coord * (5.0f * (xy_se + wh_se) + obj_se + lab)
                  + 0.5f * noobj * noobj_se;
        cell_loss *= inv_n;
    }

    // wave-64 shuffle reduction
    #pragma unroll
    for (int off = 32; off > 0; off >>= 1)
        cell_loss += __shfl_down(cell_loss, off, 64);

    __shared__ float wave_sums[4];
    int lane = threadIdx.x & 63;
    int wid  = threadIdx.x >> 6;
    if (lane == 0) wave_sums[wid] = cell_loss;
    __syncthreads();

    if (threadIdx.x == 0) {
        float s = wave_sums[0] + wave_sums[1] + wave_sums[2] + wave_sums[3];
        atomicAdd(out, s);
    }
}

extern "C" void kernel_launch(void* const* d_in, const int* in_sizes, int n_in,
                              void* d_out, int out_size, void* d_ws, size_t ws_size,
                              hipStream_t stream) {
    const float* p = (const float*)d_in[0];   // modely [N,7,7,30] f32
    const float* t = (const float*)d_in[1];   // targety [N,7,7,30] f32
    float* out = (float*)d_out;

    int ncells = in_sizes[0] / NCH;           // N*49 = 401408
    int nsamples = ncells / CELLS_PER_SAMPLE; // N = 8192
    int nvec4 = in_sizes[0] / 4;              // total float4 per array

    // d_out is poisoned before every timed launch — zero it first.
    hipMemsetAsync(out, 0, sizeof(float) * (size_t)out_size, stream);

    const int threads = 256;
    int blocks = (ncells + CPB - 1) / CPB;    // 1568, exact
    yolo_loss_kernel<<<blocks, threads, 0, stream>>>(
        (const float4*)p, (const float4*)t, out, ncells, nvec4,
        1.0f / (float)nsamples);
}

// Round 3
// 114.231 us; speedup vs baseline: 1.1083x; 1.0651x over previous
//
#include <hip/hip_runtime.h>

// YOLOv1 loss: N=8192, S=7, C=30 -> 401408 cells, 96.4 MB read, scalar out.
// Persistent wave-private double-buffered pipeline:
//   - 256 blocks x 256 threads (1 block/CU, LDS-bound), 1024 waves total.
//   - Each wave owns 2 x 15360 B LDS buffers and processes 64-cell tiles
//     (tile = 64 cells x 30 ch x 4 B = 7680 B per array).
//   - Staging via async global_load_lds (7x16B + 2x4B per array = 18 vmem
//     instrs per tile), prefetch next tile while computing current, gated by
//     fine-grained s_waitcnt vmcnt(18). No __syncthreads in the hot loop.

#define NCH 30
#define CELLS_PER_SAMPLE 49
#define TILE_CELLS 64
#define TILE_BYTES (TILE_CELLS * NCH * 4)   // 7680 per array
#define BUF_BYTES  (2 * TILE_BYTES)         // 15360: [p tile][t tile]
#define WAVE_LDS   (2 * BUF_BYTES)          // 30720: double buffer
#define NWAVES 4
#define NBLOCKS 256

__device__ __forceinline__ void gl_lds16(const char* g, char* l) {
    __builtin_amdgcn_global_load_lds(
        (const __attribute__((address_space(1))) unsigned int*)g,
        (__attribute__((address_space(3))) unsigned int*)l, 16, 0, 0);
}
__device__ __forceinline__ void gl_lds4(const char* g, char* l) {
    __builtin_amdgcn_global_load_lds(
        (const __attribute__((address_space(1))) unsigned int*)g,
        (__attribute__((address_space(3))) unsigned int*)l, 4, 0, 0);
}

// Stage one 7680-B array chunk: 7 x (64 lanes x 16 B) + 2 x (64 lanes x 4 B).
// LDS dest is wave-uniform base + lane*size (hardware adds the lane offset).
__device__ __forceinline__ void stage_array(const char* gsrc, char* ldst, int lane) {
    #pragma unroll
    for (int j = 0; j < 7; ++j)
        gl_lds16(gsrc + j * 1024 + lane * 16, ldst + j * 1024);
    gl_lds4(gsrc + 7168 + lane * 4, ldst + 7168);
    gl_lds4(gsrc + 7424 + lane * 4, ldst + 7424);
}

__device__ __forceinline__ float iou_f(float a0, float a1, float a2, float a3,
                                       float b0, float b1, float b2, float b3) {
    float xl = fmaxf(a0, b0);
    float yt = fmaxf(a1, b1);
    float xr = fminf(a2, b2);
    float yb = fminf(a3, b3);
    float ix = fmaxf(xr - xl, 0.0f);
    float iy = fmaxf(yb - yt, 0.0f);
    float inter = ix * iy;
    float aa = fabsf((a2 - a0) * (a3 - a1));
    float ba = fabsf((b2 - b0) * (b3 - b1));
    return inter / (aa + ba - inter + 1e-7f);
}

__device__ __forceinline__ float cell_loss_f(const float* __restrict__ pv,
                                             const float* __restrict__ tv,
                                             int cell) {
    int rem = cell % CELLS_PER_SAMPLE;
    int ci = rem / 7;   // row
    int cj = rem % 7;   // col

    float ltx = (float)cj / 7.0f;
    float lty = (float)ci / 7.0f;

    float coord = (tv[4] > 0.0f) ? 1.0f : 0.0f;
    float noobj = (tv[4] == 0.0f) ? 1.0f : 0.0f;

    // predicted box 1
    float b1x1 = ltx + pv[0] / 7.0f - pv[2] * 0.5f;
    float b1y1 = lty + pv[1] / 7.0f - pv[3] * 0.5f;
    float b1x2 = pv[2] + b1x1;
    float b1y2 = pv[3] + b1y1;

    // predicted box 2 (faithful: p[5:7]*(1/S - 0.5))
    const float C2 = (float)(1.0 / 7.0 - 0.5);
    float b2x1 = ltx + pv[5] * C2;
    float b2y1 = lty + pv[6] * C2;
    float b2x2 = pv[7] + b2x1;
    float b2y2 = pv[8] + b2y1;

    // target box
    float tbx1 = ltx + tv[0] / 7.0f - tv[2] * 0.5f;
    float tby1 = lty + tv[1] / 7.0f - tv[3] * 0.5f;
    float tbx2 = tv[2] + tbx1;
    float tby2 = tv[3] + tby1;

    float iou1 = iou_f(b1x1, b1y1, b1x2, b1y2, tbx1, tby1, tbx2, tby2);
    float iou2 = iou_f(b2x1, b2y1, b2x2, b2y2, tbx1, tby1, tbx2, tby2);

    bool sel = (iou1 >= iou2);
    float bx = sel ? pv[0] : pv[5];
    float by = sel ? pv[1] : pv[6];
    float bw = sel ? pv[2] : pv[7];
    float bh = sel ? pv[3] : pv[8];
    float bc = sel ? pv[4] : pv[9];

    float dx = bx - tv[0];
    float dy = by - tv[1];
    float xy_se = dx * dx + dy * dy;

    float sw = (bw > 0.0f) ? 1.0f : ((bw < 0.0f) ? -1.0f : 0.0f);
    float sh = (bh > 0.0f) ? 1.0f : ((bh < 0.0f) ? -1.0f : 0.0f);
    float dw = sw * sqrtf(fabsf(bw)) - sqrtf(tv[2]);
    float dh = sh * sqrtf(fabsf(bh)) - sqrtf(tv[3]);
    float wh_se = dw * dw + dh * dh;

    float mio = fmaxf(iou1, iou2);
    float dob = mio - bc;
    float obj_se = dob * dob;

    float d4 = pv[4] - tv[4];
    float d9 = pv[9] - tv[9];
    float noobj_se = d4 * d4 + d9 * d9;

    float lab = 0.0f;
    #pragma unroll
    for (int k = 10; k < NCH; ++k) {
        float d = pv[k] - tv[k];
        lab += d * d;
    }

    return coord * (5.0f * (xy_se + wh_se) + obj_se + lab)
         + 0.5f * noobj * noobj_se;
}

__global__ __launch_bounds__(256, 1) void yolo_loss_kernel(
    const char* __restrict__ p, const char* __restrict__ t,
    float* __restrict__ out, int ntiles, int stride_waves, float inv_n)
{
    __shared__ char lds_all[NWAVES * WAVE_LDS];   // 122880 B
    __shared__ float wave_sums[NWAVES];

    const int tid  = threadIdx.x;
    const int lane = tid & 63;
    const int wid  = tid >> 6;
    const int gw   = blockIdx.x * NWAVES + wid;   // global wave id
    char* wbase = lds_all + wid * WAVE_LDS;

    float acc = 0.0f;

    int tile = gw;
    if (tile < ntiles) {
        // prefetch first tile into buf 0
        stage_array(p + (size_t)tile * TILE_BYTES, wbase, lane);
        stage_array(t + (size_t)tile * TILE_BYTES, wbase + TILE_BYTES, lane);
    }
    int buf = 0;
    for (; tile < ntiles; tile += stride_waves) {
        int next = tile + stride_waves;
        if (next < ntiles) {
            char* nb = wbase + (buf ^ 1) * BUF_BYTES;
            stage_array(p + (size_t)next * TILE_BYTES, nb, lane);
            stage_array(t + (size_t)next * TILE_BYTES, nb + TILE_BYTES, lane);
            // 18 outstanding for next + 18 for current; wait until only the
            // next tile's 18 remain -> current tile fully landed in LDS.
            asm volatile("s_waitcnt vmcnt(18)" ::: "memory");
        } else {
            asm volatile("s_waitcnt vmcnt(0)" ::: "memory");
        }

        const float* pvp = (const float*)(wbase + buf * BUF_BYTES) + lane * NCH;
        const float* tvp = (const float*)(wbase + buf * BUF_BYTES + TILE_BYTES) + lane * NCH;

        float pv[NCH], tv[NCH];
        #pragma unroll
        for (int k = 0; k < NCH / 2; ++k) {
            float2 a = ((const float2*)pvp)[k];
            float2 b = ((const float2*)tvp)[k];
            pv[2 * k] = a.x; pv[2 * k + 1] = a.y;
            tv[2 * k] = b.x; tv[2 * k + 1] = b.y;
        }

        acc += cell_loss_f(pv, tv, tile * TILE_CELLS + lane);

        buf ^= 1;
        // all ds_reads of this buffer must complete before the next
        // global_load_lds overwrites it (next loop iteration).
        asm volatile("s_waitcnt lgkmcnt(0)" ::: "memory");
    }

    acc *= inv_n;

    // wave-64 shuffle reduction
    #pragma unroll
    for (int off = 32; off > 0; off >>= 1)
        acc += __shfl_down(acc, off, 64);

    if (lane == 0) wave_sums[wid] = acc;
    __syncthreads();
    if (tid == 0) {
        float s = wave_sums[0] + wave_sums[1] + wave_sums[2] + wave_sums[3];
        atomicAdd(out, s);
    }
}

extern "C" void kernel_launch(void* const* d_in, const int* in_sizes, int n_in,
                              void* d_out, int out_size, void* d_ws, size_t ws_size,
                              hipStream_t stream) {
    const char* p = (const char*)d_in[0];   // modely [N,7,7,30] f32
    const char* t = (const char*)d_in[1];   // targety [N,7,7,30] f32
    float* out = (float*)d_out;

    int ncells = in_sizes[0] / NCH;                  // 401408
    int nsamples = ncells / CELLS_PER_SAMPLE;        // 8192
    int ntiles = ncells / TILE_CELLS;                // 6272 (exact)
    int stride_waves = NBLOCKS * NWAVES;             // 1024

    // d_out is poisoned before every timed launch — zero it first.
    hipMemsetAsync(out, 0, sizeof(float) * (size_t)out_size, stream);

    yolo_loss_kernel<<<NBLOCKS, 256, 0, stream>>>(
        p, t, out, ntiles, stride_waves, 1.0f / (float)nsamples);
}

// Round 5
// 110.521 us; speedup vs baseline: 1.1456x; 1.0336x over previous
//
#include <hip/hip_runtime.h>

// YOLOv1 loss: N=8192, S=7, C=30 -> 401408 cells, 96.4 MB read, scalar out.
// Persistent wave-private double-buffered async pipeline, 8 waves/CU:
//   - 512 blocks x 256 threads (2 blocks/CU, LDS 61440 B/block).
//   - Tile = 32 cells = 3840 B per array; staged with 6 async
//     global_load_lds per array (3x16B + 3x4B full-wave transfers).
//     NOTE: only the 4B and 16B widths are HW-verified; the 12B variant
//     corrupted LDS (R4 NaN post-mortem) — do not use it.
//   - Each wave owns 2 x 7680 B LDS buffers; prefetch next tile while
//     computing current; gate with s_waitcnt vmcnt(12). No __syncthreads
//     in the hot loop. Compute on lanes 0-31 (1 cell/lane) -> LDS read
//     stride 120 B is a free 2-way bank alias.

#define NCH 30
#define CELLS_PER_SAMPLE 49
#define TILE_CELLS 32
#define ARR_BYTES (TILE_CELLS * NCH * 4)    // 3840 per array
#define BUF_BYTES (2 * ARR_BYTES)           // 7680: [p tile][t tile]
#define WAVE_LDS  (2 * BUF_BYTES)           // 15360: double buffer
#define NWAVES 4
#define NBLOCKS 512

__device__ __forceinline__ void gl_lds16(const char* g, char* l) {
    __builtin_amdgcn_global_load_lds(
        (const __attribute__((address_space(1))) unsigned int*)g,
        (__attribute__((address_space(3))) unsigned int*)l, 16, 0, 0);
}
__device__ __forceinline__ void gl_lds4(const char* g, char* l) {
    __builtin_amdgcn_global_load_lds(
        (const __attribute__((address_space(1))) unsigned int*)g,
        (__attribute__((address_space(3))) unsigned int*)l, 4, 0, 0);
}

// Stage one 3840-B array chunk using verified widths only:
// 3 x (64 lanes x 16 B) = 3072 B, then 3 x (64 lanes x 4 B) = 768 B.
// LDS dest is wave-uniform base + lane*size (hardware adds the lane offset).
__device__ __forceinline__ void stage_array(const char* gsrc, char* ldst, int lane) {
    gl_lds16(gsrc +    0 + lane * 16, ldst +    0);
    gl_lds16(gsrc + 1024 + lane * 16, ldst + 1024);
    gl_lds16(gsrc + 2048 + lane * 16, ldst + 2048);
    gl_lds4 (gsrc + 3072 + lane *  4, ldst + 3072);
    gl_lds4 (gsrc + 3328 + lane *  4, ldst + 3328);
    gl_lds4 (gsrc + 3584 + lane *  4, ldst + 3584);
}

__device__ __forceinline__ float iou_f(float a0, float a1, float a2, float a3,
                                       float b0, float b1, float b2, float b3) {
    float xl = fmaxf(a0, b0);
    float yt = fmaxf(a1, b1);
    float xr = fminf(a2, b2);
    float yb = fminf(a3, b3);
    float ix = fmaxf(xr - xl, 0.0f);
    float iy = fmaxf(yb - yt, 0.0f);
    float inter = ix * iy;
    float aa = fabsf((a2 - a0) * (a3 - a1));
    float ba = fabsf((b2 - b0) * (b3 - b1));
    return inter / (aa + ba - inter + 1e-7f);
}

__device__ __forceinline__ float cell_loss_f(const float* __restrict__ pv,
                                             const float* __restrict__ tv,
                                             int cell) {
    int rem = cell % CELLS_PER_SAMPLE;
    int ci = rem / 7;   // row
    int cj = rem % 7;   // col

    float ltx = (float)cj / 7.0f;
    float lty = (float)ci / 7.0f;

    float coord = (tv[4] > 0.0f) ? 1.0f : 0.0f;
    float noobj = (tv[4] == 0.0f) ? 1.0f : 0.0f;

    // predicted box 1
    float b1x1 = ltx + pv[0] / 7.0f - pv[2] * 0.5f;
    float b1y1 = lty + pv[1] / 7.0f - pv[3] * 0.5f;
    float b1x2 = pv[2] + b1x1;
    float b1y2 = pv[3] + b1y1;

    // predicted box 2 (faithful: p[5:7]*(1/S - 0.5))
    const float C2 = (float)(1.0 / 7.0 - 0.5);
    float b2x1 = ltx + pv[5] * C2;
    float b2y1 = lty + pv[6] * C2;
    float b2x2 = pv[7] + b2x1;
    float b2y2 = pv[8] + b2y1;

    // target box
    float tbx1 = ltx + tv[0] / 7.0f - tv[2] * 0.5f;
    float tby1 = lty + tv[1] / 7.0f - tv[3] * 0.5f;
    float tbx2 = tv[2] + tbx1;
    float tby2 = tv[3] + tby1;

    float iou1 = iou_f(b1x1, b1y1, b1x2, b1y2, tbx1, tby1, tbx2, tby2);
    float iou2 = iou_f(b2x1, b2y1, b2x2, b2y2, tbx1, tby1, tbx2, tby2);

    bool sel = (iou1 >= iou2);
    float bx = sel ? pv[0] : pv[5];
    float by = sel ? pv[1] : pv[6];
    float bw = sel ? pv[2] : pv[7];
    float bh = sel ? pv[3] : pv[8];
    float bc = sel ? pv[4] : pv[9];

    float dx = bx - tv[0];
    float dy = by - tv[1];
    float xy_se = dx * dx + dy * dy;

    float sw = (bw > 0.0f) ? 1.0f : ((bw < 0.0f) ? -1.0f : 0.0f);
    float sh = (bh > 0.0f) ? 1.0f : ((bh < 0.0f) ? -1.0f : 0.0f);
    float dw = sw * sqrtf(fabsf(bw)) - sqrtf(tv[2]);
    float dh = sh * sqrtf(fabsf(bh)) - sqrtf(tv[3]);
    float wh_se = dw * dw + dh * dh;

    float mio = fmaxf(iou1, iou2);
    float dob = mio - bc;
    float obj_se = dob * dob;

    float d4 = pv[4] - tv[4];
    float d9 = pv[9] - tv[9];
    float noobj_se = d4 * d4 + d9 * d9;

    float lab = 0.0f;
    #pragma unroll
    for (int k = 10; k < NCH; ++k) {
        float d = pv[k] - tv[k];
        lab += d * d;
    }

    return coord * (5.0f * (xy_se + wh_se) + obj_se + lab)
         + 0.5f * noobj * noobj_se;
}

__global__ __launch_bounds__(256, 2) void yolo_loss_kernel(
    const char* __restrict__ p, const char* __restrict__ t,
    float* __restrict__ out, int ntiles, int stride_waves, float inv_n)
{
    __shared__ char lds_all[NWAVES * WAVE_LDS];   // 61440 B
    __shared__ float wave_sums[NWAVES];

    const int tid  = threadIdx.x;
    const int lane = tid & 63;
    const int wid  = tid >> 6;
    const int gw   = blockIdx.x * NWAVES + wid;   // global wave id
    char* wbase = lds_all + wid * WAVE_LDS;

    float acc = 0.0f;

    int tile = gw;
    if (tile < ntiles) {
        // prefetch first tile into buf 0
        stage_array(p + (size_t)tile * ARR_BYTES, wbase, lane);
        stage_array(t + (size_t)tile * ARR_BYTES, wbase + ARR_BYTES, lane);
    }
    int buf = 0;
    for (; tile < ntiles; tile += stride_waves) {
        int next = tile + stride_waves;
        if (next < ntiles) {
            char* nb = wbase + (buf ^ 1) * BUF_BYTES;
            stage_array(p + (size_t)next * ARR_BYTES, nb, lane);
            stage_array(t + (size_t)next * ARR_BYTES, nb + ARR_BYTES, lane);
            // 12 outstanding for next + 12 for current; wait until only the
            // next tile's 12 remain -> current tile fully landed in LDS.
            asm volatile("s_waitcnt vmcnt(12)" ::: "memory");
        } else {
            asm volatile("s_waitcnt vmcnt(0)" ::: "memory");
        }

        if (lane < TILE_CELLS) {
            const float* pvp = (const float*)(wbase + buf * BUF_BYTES) + lane * NCH;
            const float* tvp = (const float*)(wbase + buf * BUF_BYTES + ARR_BYTES) + lane * NCH;

            float pv[NCH], tv[NCH];
            #pragma unroll
            for (int k = 0; k < NCH / 2; ++k) {
                float2 a = ((const float2*)pvp)[k];
                float2 b = ((const float2*)tvp)[k];
                pv[2 * k] = a.x; pv[2 * k + 1] = a.y;
                tv[2 * k] = b.x; tv[2 * k + 1] = b.y;
            }

            acc += cell_loss_f(pv, tv, tile * TILE_CELLS + lane);
        }

        buf ^= 1;
        // all ds_reads of this buffer must complete before the next
        // global_load_lds overwrites it (next loop iteration).
        asm volatile("s_waitcnt lgkmcnt(0)" ::: "memory");
    }

    acc *= inv_n;

    // wave-64 shuffle reduction
    #pragma unroll
    for (int off = 32; off > 0; off >>= 1)
        acc += __shfl_down(acc, off, 64);

    if (lane == 0) wave_sums[wid] = acc;
    __syncthreads();
    if (tid == 0) {
        float s = wave_sums[0] + wave_sums[1] + wave_sums[2] + wave_sums[3];
        atomicAdd(out, s);
    }
}

extern "C" void kernel_launch(void* const* d_in, const int* in_sizes, int n_in,
                              void* d_out, int out_size, void* d_ws, size_t ws_size,
                              hipStream_t stream) {
    const char* p = (const char*)d_in[0];   // modely [N,7,7,30] f32
    const char* t = (const char*)d_in[1];   // targety [N,7,7,30] f32
    float* out = (float*)d_out;

    int ncells = in_sizes[0] / NCH;                  // 401408
    int nsamples = ncells / CELLS_PER_SAMPLE;        // 8192
    int ntiles = ncells / TILE_CELLS;                // 12544 (exact)
    int stride_waves = NBLOCKS * NWAVES;             // 2048

    // d_out is poisoned before every timed launch — zero it first.
    hipMemsetAsync(out, 0, sizeof(float) * (size_t)out_size, stream);

    yolo_loss_kernel<<<NBLOCKS, 256, 0, stream>>>(
        p, t, out, ntiles, stride_waves, 1.0f / (float)nsamples);
}